// Round 2
// baseline (2199.146 us; speedup 1.0000x reference)
//
#include <hip/hip_runtime.h>
#include <stdint.h>

// BitLinear: ternary groupwise quant (group=128) of W[16384][4096], then
// out[8192][16384] = X[8192][4096] . Wq^T + bias, fp32 out.
// Strategy: quantize W -> bf16 in ws, convert X -> bf16 in ws, then
// m97-structure bf16 MFMA GEMM (128x128 tile, BK=32, global_load_lds w=16).
// ws usage: (16384*4096 + 8192*4096) * 2B = 192 MiB.

#define D_IN   4096
#define D_OUT  16384
#define M_ROWS 8192
#define GROUPS_PER_ROW 32   // 4096 / 128

typedef short short8 __attribute__((ext_vector_type(8)));
typedef float f32x4 __attribute__((ext_vector_type(4)));

typedef __attribute__((address_space(1))) const void* as1cv;
typedef __attribute__((address_space(3))) void* as3v;

__device__ __forceinline__ unsigned short f2bf(float f) {
    // round-to-nearest-even fp32 -> bf16 bit pattern
    unsigned int u = __float_as_uint(f);
    u += 0x7fffu + ((u >> 16) & 1u);
    return (unsigned short)(u >> 16);
}

// ---- weight ternary quantize: one 64-lane wave per 128-element group ----
__global__ void quant_w(const float* __restrict__ W, unsigned short* __restrict__ Wq) {
    int g    = blockIdx.x * 4 + (threadIdx.x >> 6);   // group index
    int lane = threadIdx.x & 63;
    size_t base = (size_t)g * 128 + (size_t)lane * 2;
    float2 v = *(const float2*)(W + base);
    float s = fabsf(v.x) + fabsf(v.y);
    #pragma unroll
    for (int off = 32; off >= 1; off >>= 1) s += __shfl_xor(s, off);
    float scale = fmaxf(s * (1.0f / 128.0f), 1e-8f);
    // replicate reference fp32 division for the threshold compare
    float na = v.x / scale;
    float nb = v.y / scale;
    float qa = (na > 0.5f) ? scale : ((na < -0.5f) ? -scale : 0.0f);
    float qb = (nb > 0.5f) ? scale : ((nb < -0.5f) ? -scale : 0.0f);
    unsigned int packed = (unsigned int)f2bf(qa) | ((unsigned int)f2bf(qb) << 16);
    *(unsigned int*)(Wq + base) = packed;
}

// ---- X fp32 -> bf16 ----
__global__ void conv_x(const float4* __restrict__ X, ushort4* __restrict__ Xb, int n4) {
    int idx    = blockIdx.x * blockDim.x + threadIdx.x;
    int stride = gridDim.x * blockDim.x;
    for (int i = idx; i < n4; i += stride) {
        float4 v = X[i];
        ushort4 o;
        o.x = f2bf(v.x); o.y = f2bf(v.y); o.z = f2bf(v.z); o.w = f2bf(v.w);
        Xb[i] = o;
    }
}

// ---- bf16 GEMM, B^T input (both A and B stored K-major), m97 structure ----
// A: [8192][4096] bf16 bits, B: [16384][4096] bf16 bits, Out: [8192][16384] f32
__global__ void gemm_bt(const unsigned short* __restrict__ A,
                        const unsigned short* __restrict__ B,
                        const float* __restrict__ bias,
                        float* __restrict__ Out)
{
    __shared__ unsigned short As[128 * 32];   // [row 0..127][k 0..31], 64B rows
    __shared__ unsigned short Bs[128 * 32];

    // XCD-aware swizzle: grid = 8192, 8192 % 8 == 0 -> simple bijective form
    int bid = blockIdx.x;
    int cpx = gridDim.x >> 3;
    int swz = (bid & 7) * cpx + (bid >> 3);
    int bm  = swz >> 7;      // 64 m-blocks
    int bn  = swz & 127;     // 128 n-blocks (fast dim: share A panel in L2)

    int tid  = threadIdx.x;
    int wid  = tid >> 6;
    int lane = tid & 63;
    int wr = wid >> 1, wc = wid & 1;   // 2x2 waves -> each owns 64x64
    int fr = lane & 15;
    int fq = lane >> 4;

    const unsigned short* Abase = A + (size_t)(bm * 128) * D_IN;
    const unsigned short* Bbase = B + (size_t)(bn * 128) * D_IN;

    int srow = lane >> 2;          // staging: row within 16-row chunk
    int skh  = (lane & 3) * 8;     // halfword offset within 64B row

    f32x4 acc[4][4];
    #pragma unroll
    for (int i = 0; i < 4; ++i)
        #pragma unroll
        for (int j = 0; j < 4; ++j)
            acc[i][j] = (f32x4){0.f, 0.f, 0.f, 0.f};

    for (int kt = 0; kt < D_IN / 32; ++kt) {
        int k0 = kt * 32;
        __syncthreads();   // previous tile fully consumed
        #pragma unroll
        for (int c = 0; c < 2; ++c) {
            int chunk = wid * 2 + c;           // wave-uniform
            int row   = chunk * 16 + srow;
            __builtin_amdgcn_global_load_lds(
                (as1cv)(Abase + (size_t)row * D_IN + k0 + skh),
                (as3v)(As + chunk * 512), 16, 0, 0);
            __builtin_amdgcn_global_load_lds(
                (as1cv)(Bbase + (size_t)row * D_IN + k0 + skh),
                (as3v)(Bs + chunk * 512), 16, 0, 0);
        }
        __syncthreads();   // staging drained (compiler emits vmcnt(0) before barrier)

        short8 af[4], bf[4];
        #pragma unroll
        for (int i = 0; i < 4; ++i)
            af[i] = *(const short8*)(As + (wr * 64 + i * 16 + fr) * 32 + fq * 8);
        #pragma unroll
        for (int j = 0; j < 4; ++j)
            bf[j] = *(const short8*)(Bs + (wc * 64 + j * 16 + fr) * 32 + fq * 8);

        #pragma unroll
        for (int i = 0; i < 4; ++i)
            #pragma unroll
            for (int j = 0; j < 4; ++j)
                acc[i][j] = __builtin_amdgcn_mfma_f32_16x16x32_bf16(
                    af[i], bf[j], acc[i][j], 0, 0, 0);
    }

    // C/D layout (measured): col = lane&15, row = (lane>>4)*4 + reg
    int row0 = bm * 128 + wr * 64 + fq * 4;
    int col0 = bn * 128 + wc * 64 + fr;
    #pragma unroll
    for (int i = 0; i < 4; ++i)
        #pragma unroll
        for (int j = 0; j < 4; ++j) {
            int col  = col0 + j * 16;
            float bz = bias[col];
            #pragma unroll
            for (int r = 0; r < 4; ++r)
                Out[(size_t)(row0 + i * 16 + r) * D_OUT + col] = acc[i][j][r] + bz;
        }
}

extern "C" void kernel_launch(void* const* d_in, const int* in_sizes, int n_in,
                              void* d_out, int out_size, void* d_ws, size_t ws_size,
                              hipStream_t stream) {
    const float* x    = (const float*)d_in[0];   // [4][2048][4096]
    const float* w    = (const float*)d_in[1];   // [16384][4096]
    const float* bias = (const float*)d_in[2];   // [16384]
    float* out = (float*)d_out;                  // [4][2048][16384]

    unsigned short* wq = (unsigned short*)d_ws;                 // 134 MiB
    unsigned short* xb = wq + (size_t)D_OUT * D_IN;             // +64 MiB

    quant_w<<<(D_OUT * GROUPS_PER_ROW) / 4, 256, 0, stream>>>(w, wq);
    conv_x<<<2048, 256, 0, stream>>>((const float4*)x, (ushort4*)xb,
                                     (M_ROWS * D_IN) / 4);
    gemm_bt<<<(M_ROWS / 128) * (D_OUT / 128), 256, 0, stream>>>(xb, wq, bias, out);
}